// Round 13
// baseline (262.159 us; speedup 1.0000x reference)
//
#include <hip/hip_runtime.h>

using i32x4  = __attribute__((ext_vector_type(4))) int;
using i32x16 = __attribute__((ext_vector_type(16))) int;

constexpr int K_DIM = 4096;   // N_IN
constexpr int N_DIM = 4096;   // N_OUT
constexpr float QBf = 128.0f;
constexpr float EPf = 0.01f;
constexpr float LN_EPSf = 1e-5f;

#define GLOAD_LDS16(gp, lp)                                                  \
    __builtin_amdgcn_global_load_lds(                                        \
        (const __attribute__((address_space(1))) void*)(gp),                 \
        (__attribute__((address_space(3))) void*)(lp), 16, 0, 0)

#define BARRIER()                                                            \
    do { asm volatile("" ::: "memory");                                      \
         __builtin_amdgcn_s_barrier();                                       \
         asm volatile("" ::: "memory"); } while (0)

#define WAIT_LGKM(N)                                                         \
    do { asm volatile("s_waitcnt lgkmcnt(" #N ")" ::: "memory");             \
         __builtin_amdgcn_sched_barrier(0); } while (0)

// ---------------------------------------------------------------------------
// Kernel 1: fused LayerNorm + ABSMax-quant + round-to-int8.  One block/row.
// ---------------------------------------------------------------------------
__global__ __launch_bounds__(256) void ln_quant_kernel(
    const float* __restrict__ x,
    const float* __restrict__ ln_g,
    const float* __restrict__ ln_b,
    const float* __restrict__ gamma_p,
    char* __restrict__ xq)
{
    const int row = blockIdx.x;
    const int t = threadIdx.x;
    const float4* xr4 = reinterpret_cast<const float4*>(x + (size_t)row * K_DIM);

    float4 v[4];
    float sum = 0.f, sumsq = 0.f;
#pragma unroll
    for (int i = 0; i < 4; ++i) {
        v[i] = xr4[t * 4 + i];
        sum += v[i].x + v[i].y + v[i].z + v[i].w;
        sumsq += v[i].x * v[i].x + v[i].y * v[i].y + v[i].z * v[i].z + v[i].w * v[i].w;
    }
#pragma unroll
    for (int off = 32; off > 0; off >>= 1) {
        sum += __shfl_down(sum, off);
        sumsq += __shfl_down(sumsq, off);
    }
    __shared__ float s_sum[4], s_sq[4];
    const int lane = t & 63, w = t >> 6;
    if (lane == 0) { s_sum[w] = sum; s_sq[w] = sumsq; }
    __syncthreads();
    sum = s_sum[0] + s_sum[1] + s_sum[2] + s_sum[3];
    sumsq = s_sq[0] + s_sq[1] + s_sq[2] + s_sq[3];

    const float mu = sum * (1.0f / K_DIM);
    const float var = sumsq * (1.0f / K_DIM) - mu * mu;
    const float rstd = rsqrtf(var + LN_EPSf);
    const float qs = QBf / gamma_p[0];
    const float lo = -QBf + EPf, hi = QBf - EPf;

    alignas(16) char ob[16];
#pragma unroll
    for (int i = 0; i < 4; ++i) {
        const float4 g = reinterpret_cast<const float4*>(ln_g)[t * 4 + i];
        const float4 b = reinterpret_cast<const float4*>(ln_b)[t * 4 + i];
        const float f0 = fminf(fmaxf(((v[i].x - mu) * rstd * g.x + b.x) * qs, lo), hi);
        const float f1 = fminf(fmaxf(((v[i].y - mu) * rstd * g.y + b.y) * qs, lo), hi);
        const float f2 = fminf(fmaxf(((v[i].z - mu) * rstd * g.z + b.z) * qs, lo), hi);
        const float f3 = fminf(fmaxf(((v[i].w - mu) * rstd * g.w + b.w) * qs, lo), hi);
        int x0 = (int)rintf(f0), x1 = (int)rintf(f1);
        int x2 = (int)rintf(f2), x3 = (int)rintf(f3);
        ob[i * 4 + 0] = (char)(x0 > 127 ? 127 : x0);
        ob[i * 4 + 1] = (char)(x1 > 127 ? 127 : x1);
        ob[i * 4 + 2] = (char)(x2 > 127 ? 127 : x2);
        ob[i * 4 + 3] = (char)(x3 > 127 ? 127 : x3);
    }
    *reinterpret_cast<uint4*>(xq + (size_t)row * K_DIM + t * 16) =
        *reinterpret_cast<const uint4*>(ob);
}

// ---------------------------------------------------------------------------
// Kernel 2: w (fp32, K x N, values ±1) -> wq (int8, N x K).  64x64 tiles.
// ---------------------------------------------------------------------------
__global__ __launch_bounds__(256) void wtrans_kernel(
    const float* __restrict__ w, char* __restrict__ wq)
{
    __shared__ char tile[64][68];
    const int t = threadIdx.x;
    const int bk = blockIdx.y * 64;
    const int bn = blockIdx.x * 64;
#pragma unroll
    for (int i = 0; i < 4; ++i) {
        const int li = i * 1024 + t * 4;
        const int r = li >> 6, c = li & 63;    // r = k-in-tile, c = n-in-tile
        const float4 vv = *reinterpret_cast<const float4*>(
            w + (size_t)(bk + r) * N_DIM + bn + c);
        tile[r][c]     = (char)vv.x;
        tile[r][c + 1] = (char)vv.y;
        tile[r][c + 2] = (char)vv.z;
        tile[r][c + 3] = (char)vv.w;
    }
    __syncthreads();
    const int n = t >> 2, kc = t & 3;
    alignas(16) char h16[16];
#pragma unroll
    for (int j = 0; j < 16; ++j) h16[j] = tile[kc * 16 + j][n];
    *reinterpret_cast<uint4*>(wq + (size_t)(bn + n) * K_DIM + bk + kc * 16) =
        *reinterpret_cast<const uint4*>(h16);
}

// ---------------------------------------------------------------------------
// Kernel 3: GEMM  C[M,N] = A[M,K] * Bt[N,K]^T * scale  (i8 MFMA, i32 acc)
// 256x256 tile, BK=64 (64 K-tiles), 512 threads = 8 waves (2M x 4N),
// wave tile 128x64 (4 mf x 2 nf x 2 ks = 16 mfma_i32_32x32x32_i8 per tile).
// ONE FAT PHASE PER K-TILE + cross-tile register read-ahead:
//   tile t: { read B(t) frags x4 from buf t%3
//           | read-ahead A(t+1) frags x8 from buf (t+1)%3  [published!]
//           | stage tile t+2 -> buf (t+2)%3  (4 global_load_lds)
//           | lgkm(8): A(t)+B(t) complete, A(t+1)'s 8 still flying
//           | 16 back-to-back MFMA  (1171 SIMD-cy uninterrupted)
//           | vmcnt(0) [stage issued ~1 tile ago - covered] | BARRIER }
// Ring ledger: buf (t+1)%3 staged at t-1, vmcnt(0)+barrier at end of t-1 =>
// published before t's read-ahead.  Stage target buf (t+2)%3's last readers
// ran at t-1 (lgkm-complete before its barrier).  All counted waits are
// memory-clobber asm (order pinned); sched_barrier(0) per rule #18.
// LDS/buffer: 3 x 32K = 96 KiB; per buffer A 16K @0, B 16K @16384, layout
// [kc 0..3][row 0..255][16B] -> 32-lane frag reads are 512 contiguous bytes
// (zero bank conflicts); staging dest linear in t.
// Registers: afr[2][8] (64) + bfr[4] (16) + acc 128 AGPR ~= 243/wave
// -> keeps 2 waves/SIMD.
// ---------------------------------------------------------------------------
__global__ __launch_bounds__(512, 2) void gemm_kernel(
    const char* __restrict__ A,
    const char* __restrict__ Bt,
    float* __restrict__ C,
    const float* __restrict__ beta_p,
    const float* __restrict__ gamma_p)
{
    constexpr int NT = K_DIM / 64;                 // 64 K-tiles
    __shared__ __align__(16) char lds[98304];      // 3 bufs x (A 16K | B 16K)

    const int t = threadIdx.x;
    // ---- XCD swizzle: flat id -> 8x8 square per XCD (512 blocks, 16x32 grid)
    const int flat = blockIdx.y * gridDim.x + blockIdx.x;
    const int xcd = flat & 7;
    const int r8 = flat >> 3;                       // 0..63
    const int by = ((xcd >> 1) << 3) + (r8 >> 3);   // 0..31  (M index)
    const int bx = ((xcd & 1) << 3) + (r8 & 7);     // 0..15  (N index)
    const int bm = by * 256;
    const int bn = bx * 256;

    const int lane = t & 63;
    const int w = t >> 6;
    const int wm = w >> 2;            // 0..1
    const int wn = w & 3;             // 0..3
    const int ln31 = lane & 31;
    const int lg2 = lane >> 5;        // 0..1

    const char* gA = A + (size_t)bm * K_DIM;
    const char* gB = Bt + (size_t)bn * K_DIM;
    // staging: thread t covers row (t&255), k-chunks (t>>8) and (t>>8)+2
    const int voff = (t & 255) * K_DIM + ((t >> 8) << 4);

    // fragment read offsets within a buffer region ([kc][row][16B], plane 4KB)
    const int aoff = lg2 * 4096 + ((wm * 128 + ln31) << 4);
    const int boff = lg2 * 4096 + ((wn * 64 + ln31) << 4);

#define STAGE(B, kt)                                                          \
    do {                                                                      \
        GLOAD_LDS16(gA + (size_t)(kt) * 64 + voff,                            \
                    lds + (B) * 32768 + t * 16);                              \
        GLOAD_LDS16(gA + (size_t)(kt) * 64 + voff + 32,                       \
                    lds + (B) * 32768 + 8192 + t * 16);                       \
        GLOAD_LDS16(gB + (size_t)(kt) * 64 + voff,                            \
                    lds + (B) * 32768 + 16384 + t * 16);                      \
        GLOAD_LDS16(gB + (size_t)(kt) * 64 + voff + 32,                       \
                    lds + (B) * 32768 + 16384 + 8192 + t * 16);               \
    } while (0)

#define LD(p) (*reinterpret_cast<const i32x4*>(p))

#define READ_B(BUFI)                                                          \
    do {                                                                      \
        const char* bb_ = lds + (BUFI) * 32768 + 16384;                       \
        _Pragma("unroll")                                                     \
        for (int ks = 0; ks < 2; ++ks)                                        \
            _Pragma("unroll")                                                 \
            for (int nf = 0; nf < 2; ++nf)                                    \
                bfr[ks * 2 + nf] = LD(bb_ + ks * 8192 + nf * 512 + boff);     \
    } while (0)

#define READ_AH(PN, BUFI)                                                     \
    do {                                                                      \
        const char* an_ = lds + (BUFI) * 32768;                               \
        _Pragma("unroll")                                                     \
        for (int ks = 0; ks < 2; ++ks)                                        \
            _Pragma("unroll")                                                 \
            for (int mf = 0; mf < 4; ++mf)                                    \
                afr[PN][ks * 4 + mf] = LD(an_ + ks * 8192 + mf * 512 + aoff); \
    } while (0)

#define MFMA16(P)                                                             \
    do {                                                                      \
        __builtin_amdgcn_s_setprio(1);                                        \
        _Pragma("unroll")                                                     \
        for (int ks = 0; ks < 2; ++ks)                                        \
            _Pragma("unroll")                                                 \
            for (int mf = 0; mf < 4; ++mf)                                    \
                _Pragma("unroll")                                             \
                for (int nf = 0; nf < 2; ++nf)                                \
                    acc[mf][nf] = __builtin_amdgcn_mfma_i32_32x32x32_i8(      \
                        afr[P][ks * 4 + mf], bfr[ks * 2 + nf],                \
                        acc[mf][nf], 0, 0, 0);                                \
        __builtin_amdgcn_s_setprio(0);                                        \
    } while (0)

// BC=cur buf, BN_=next buf, BS=stage buf, P=cur parity, PN=next parity,
// RD/ST = compile-time do-read-ahead / do-stage flags, tt = runtime tile idx
#define TILE(BC, BN_, BS, P, PN, RD, ST, tt)                                  \
    do {                                                                      \
        READ_B(BC);                                                           \
        if (RD) READ_AH(PN, BN_);                                             \
        if (ST) STAGE(BS, (tt) + 2);                                          \
        if (RD) { WAIT_LGKM(8); } else { WAIT_LGKM(0); }                      \
        MFMA16(P);                                                            \
        asm volatile("s_waitcnt vmcnt(0)" ::: "memory");                      \
        BARRIER();                                                            \
    } while (0)

    i32x16 acc[4][2];
#pragma unroll
    for (int m = 0; m < 4; ++m)
#pragma unroll
        for (int n = 0; n < 2; ++n)
#pragma unroll
            for (int q = 0; q < 16; ++q)
                acc[m][n][q] = 0;

    i32x4 afr[2][8];
    i32x4 bfr[4];

    // prologue: stage tiles 0,1 -> bufs 0,1; publish; read-ahead tile 0's A
    STAGE(0, 0); STAGE(1, 1);
    asm volatile("s_waitcnt vmcnt(0)" ::: "memory");
    BARRIER();
    READ_AH(0, 0);

    // 60 tiles in 10 groups of 6 (buf mod 3 x parity mod 2), + 4 tail tiles
    for (int kt = 0; kt < NT - 4; kt += 6) {
        TILE(0, 1, 2, 0, 1, 1, 1, kt);
        TILE(1, 2, 0, 1, 0, 1, 1, kt + 1);
        TILE(2, 0, 1, 0, 1, 1, 1, kt + 2);
        TILE(0, 1, 2, 1, 0, 1, 1, kt + 3);
        TILE(1, 2, 0, 0, 1, 1, 1, kt + 4);
        TILE(2, 0, 1, 1, 0, 1, 1, kt + 5);
    }
    TILE(0, 1, 2, 0, 1, 1, 1, NT - 4);   // tile 60, stages 62
    TILE(1, 2, 0, 1, 0, 1, 1, NT - 3);   // tile 61, stages 63
    TILE(2, 0, 1, 0, 1, 1, 0, NT - 2);   // tile 62, no stage
    TILE(0, 1, 2, 1, 0, 0, 0, NT - 1);   // tile 63, no read-ahead

    // ---- epilogue: 32x32 C/D layout: col=lane&31,
    //      row = (reg&3) + 8*(reg>>2) + 4*(lane>>5) ----
    const float scale = beta_p[0] * gamma_p[0] * (1.0f / QBf);
    const int orow0 = bm + wm * 128 + lg2 * 4;
    const int ocol0 = bn + wn * 64 + ln31;
#pragma unroll
    for (int mf = 0; mf < 4; ++mf) {
#pragma unroll
        for (int nf = 0; nf < 2; ++nf) {
#pragma unroll
            for (int reg = 0; reg < 16; ++reg) {
                const int row = orow0 + mf * 32 + (reg & 3) + 8 * (reg >> 2);
                C[(size_t)row * N_DIM + ocol0 + nf * 32] =
                    (float)acc[mf][nf][reg] * scale;
            }
        }
    }
#undef STAGE
#undef LD
#undef READ_B
#undef READ_AH
#undef MFMA16
#undef TILE
}

// ---------------------------------------------------------------------------
extern "C" void kernel_launch(void* const* d_in, const int* in_sizes, int n_in,
                              void* d_out, int out_size, void* d_ws, size_t ws_size,
                              hipStream_t stream)
{
    const float* x       = (const float*)d_in[0];
    const float* w       = (const float*)d_in[1];
    const float* ln_g    = (const float*)d_in[2];
    const float* ln_b    = (const float*)d_in[3];
    const float* beta_p  = (const float*)d_in[4];
    const float* gamma_p = (const float*)d_in[5];
    float* out = (float*)d_out;

    const int M = in_sizes[0] / K_DIM;   // 8192

    char* xq = (char*)d_ws;
    char* wq = (char*)d_ws + (size_t)M * K_DIM;

    ln_quant_kernel<<<M, 256, 0, stream>>>(x, ln_g, ln_b, gamma_p, xq);
    wtrans_kernel<<<dim3(N_DIM / 64, K_DIM / 64), 256, 0, stream>>>(w, wq);
    gemm_kernel<<<dim3(N_DIM / 256, M / 256), 512, 0, stream>>>(xq, wq, out, beta_p, gamma_p);
}

// Round 14
// 255.354 us; speedup vs baseline: 1.0266x; 1.0266x over previous
//
#include <hip/hip_runtime.h>

using i32x4  = __attribute__((ext_vector_type(4))) int;
using i32x16 = __attribute__((ext_vector_type(16))) int;

constexpr int K_DIM = 4096;   // N_IN
constexpr int N_DIM = 4096;   // N_OUT
constexpr float QBf = 128.0f;
constexpr float EPf = 0.01f;
constexpr float LN_EPSf = 1e-5f;

#define GLOAD_LDS16(gp, lp)                                                  \
    __builtin_amdgcn_global_load_lds(                                        \
        (const __attribute__((address_space(1))) void*)(gp),                 \
        (__attribute__((address_space(3))) void*)(lp), 16, 0, 0)

#define BARRIER()                                                            \
    do { asm volatile("" ::: "memory");                                      \
         __builtin_amdgcn_s_barrier();                                       \
         asm volatile("" ::: "memory"); } while (0)

#define WAIT_LGKM(N)                                                         \
    do { asm volatile("s_waitcnt lgkmcnt(" #N ")" ::: "memory");             \
         __builtin_amdgcn_sched_barrier(0); } while (0)

// ---------------------------------------------------------------------------
// Kernel 1: fused LayerNorm + ABSMax-quant + round-to-int8.  One block/row.
// ---------------------------------------------------------------------------
__global__ __launch_bounds__(256) void ln_quant_kernel(
    const float* __restrict__ x,
    const float* __restrict__ ln_g,
    const float* __restrict__ ln_b,
    const float* __restrict__ gamma_p,
    char* __restrict__ xq)
{
    const int row = blockIdx.x;
    const int t = threadIdx.x;
    const float4* xr4 = reinterpret_cast<const float4*>(x + (size_t)row * K_DIM);

    float4 v[4];
    float sum = 0.f, sumsq = 0.f;
#pragma unroll
    for (int i = 0; i < 4; ++i) {
        v[i] = xr4[t * 4 + i];
        sum += v[i].x + v[i].y + v[i].z + v[i].w;
        sumsq += v[i].x * v[i].x + v[i].y * v[i].y + v[i].z * v[i].z + v[i].w * v[i].w;
    }
#pragma unroll
    for (int off = 32; off > 0; off >>= 1) {
        sum += __shfl_down(sum, off);
        sumsq += __shfl_down(sumsq, off);
    }
    __shared__ float s_sum[4], s_sq[4];
    const int lane = t & 63, w = t >> 6;
    if (lane == 0) { s_sum[w] = sum; s_sq[w] = sumsq; }
    __syncthreads();
    sum = s_sum[0] + s_sum[1] + s_sum[2] + s_sum[3];
    sumsq = s_sq[0] + s_sq[1] + s_sq[2] + s_sq[3];

    const float mu = sum * (1.0f / K_DIM);
    const float var = sumsq * (1.0f / K_DIM) - mu * mu;
    const float rstd = rsqrtf(var + LN_EPSf);
    const float qs = QBf / gamma_p[0];
    const float lo = -QBf + EPf, hi = QBf - EPf;

    alignas(16) char ob[16];
#pragma unroll
    for (int i = 0; i < 4; ++i) {
        const float4 g = reinterpret_cast<const float4*>(ln_g)[t * 4 + i];
        const float4 b = reinterpret_cast<const float4*>(ln_b)[t * 4 + i];
        const float f0 = fminf(fmaxf(((v[i].x - mu) * rstd * g.x + b.x) * qs, lo), hi);
        const float f1 = fminf(fmaxf(((v[i].y - mu) * rstd * g.y + b.y) * qs, lo), hi);
        const float f2 = fminf(fmaxf(((v[i].z - mu) * rstd * g.z + b.z) * qs, lo), hi);
        const float f3 = fminf(fmaxf(((v[i].w - mu) * rstd * g.w + b.w) * qs, lo), hi);
        int x0 = (int)rintf(f0), x1 = (int)rintf(f1);
        int x2 = (int)rintf(f2), x3 = (int)rintf(f3);
        ob[i * 4 + 0] = (char)(x0 > 127 ? 127 : x0);
        ob[i * 4 + 1] = (char)(x1 > 127 ? 127 : x1);
        ob[i * 4 + 2] = (char)(x2 > 127 ? 127 : x2);
        ob[i * 4 + 3] = (char)(x3 > 127 ? 127 : x3);
    }
    *reinterpret_cast<uint4*>(xq + (size_t)row * K_DIM + t * 16) =
        *reinterpret_cast<const uint4*>(ob);
}

// ---------------------------------------------------------------------------
// Kernel 2: w (fp32, K x N, values ±1) -> wq (int8, N x K).  64x64 tiles.
// ---------------------------------------------------------------------------
__global__ __launch_bounds__(256) void wtrans_kernel(
    const float* __restrict__ w, char* __restrict__ wq)
{
    __shared__ char tile[64][68];
    const int t = threadIdx.x;
    const int bk = blockIdx.y * 64;
    const int bn = blockIdx.x * 64;
#pragma unroll
    for (int i = 0; i < 4; ++i) {
        const int li = i * 1024 + t * 4;
        const int r = li >> 6, c = li & 63;    // r = k-in-tile, c = n-in-tile
        const float4 vv = *reinterpret_cast<const float4*>(
            w + (size_t)(bk + r) * N_DIM + bn + c);
        tile[r][c]     = (char)vv.x;
        tile[r][c + 1] = (char)vv.y;
        tile[r][c + 2] = (char)vv.z;
        tile[r][c + 3] = (char)vv.w;
    }
    __syncthreads();
    const int n = t >> 2, kc = t & 3;
    alignas(16) char h16[16];
#pragma unroll
    for (int j = 0; j < 16; ++j) h16[j] = tile[kc * 16 + j][n];
    *reinterpret_cast<uint4*>(wq + (size_t)(bn + n) * K_DIM + bk + kc * 16) =
        *reinterpret_cast<const uint4*>(h16);
}

// ---------------------------------------------------------------------------
// Kernel 3: GEMM  C[M,N] = A[M,K] * Bt[N,K]^T * scale  (i8 MFMA, i32 acc)
// 256x256 tile, BK=64 (64 K-tiles), 512 threads = 8 waves (2M x 4N),
// wave tile 128x64 (4 mf x 2 nf x 2 ks = 16 mfma_i32_32x32x32_i8 / K-tile).
// R11's interleaved lgkm(2) chain + B-READ-AHEAD via deep B-ring:
//   LDS: A 2-buf (2x16K @0) + B 4-buf (4x16K @32K) = 96 KiB.
//   Tile t: A in abuf t&1, B frags ALREADY IN REGISTERS (read at t-1 p3
//   from bbuf (t)&3, which was staged at t-3 and vmcnt-published at end of
//   t-2... staged at t-3 p0, forced by end-of-(t-1... see ledger below).
//   Post-barrier critical path = 2 A-reads only (was 8 B + 2 A).
// Per tile (4 phases, 1 barrier):
//   R0: A(ks0,mf01)
//   p0: A(ks0,mf23) | STAGE_A(t+1)->a^1, STAGE_B(t+3)->b(t+3)&3
//       | lgkm(2) | MFMA(ks0,mf01)
//   p1: A(ks1,mf01) | lgkm(2) | MFMA(ks0,mf23)
//   p2: A(ks1,mf23) | lgkm(2) | MFMA(ks1,mf01)
//   p3: B-AHEAD(t+1): 4 reads from b(t+1)&3 | lgkm(4) | MFMA(ks1,mf23)
//   end: vmcnt(2) [leaves B(t+3) flying; forces A(t+1), B(t+2)] | BARRIER
// Ledger: B(t+1) staged at t-2 p0, forced by end-of-(t-1) vmcnt(2) (FIFO:
// newest 2 at that point = B(t+2)) -> published before t's p3 read-ahead.
// B-stage target b(t+3)&3 = b(t-1)&3: its last readers (B-ahead at t-2 p3)
// are lgkm-complete by t-1 p0; two barriers separate them from the stage.
// A-stage target a^1: tile t-1's A reads complete by its p3 lgkm(4).
// Registers: afr 16 + bfrA/bfrB 32 + acc 128 AGPR + addr ~50 ~= 225 < 256.
// ---------------------------------------------------------------------------
__global__ __launch_bounds__(512, 2) void gemm_kernel(
    const char* __restrict__ A,
    const char* __restrict__ Bt,
    float* __restrict__ C,
    const float* __restrict__ beta_p,
    const float* __restrict__ gamma_p)
{
    constexpr int NT = K_DIM / 64;                 // 64 K-tiles
    __shared__ __align__(16) char lds[98304];      // A 2x16K | B 4x16K

    const int t = threadIdx.x;
    // ---- XCD swizzle: flat id -> 8x8 square per XCD (512 blocks, 16x32 grid)
    const int flat = blockIdx.y * gridDim.x + blockIdx.x;
    const int xcd = flat & 7;
    const int r8 = flat >> 3;                       // 0..63
    const int by = ((xcd >> 1) << 3) + (r8 >> 3);   // 0..31  (M index)
    const int bx = ((xcd & 1) << 3) + (r8 & 7);     // 0..15  (N index)
    const int bm = by * 256;
    const int bn = bx * 256;

    const int lane = t & 63;
    const int w = t >> 6;
    const int wm = w >> 2;            // 0..1
    const int wn = w & 3;             // 0..3
    const int ln31 = lane & 31;
    const int lg2 = lane >> 5;        // 0..1

    const char* gA = A + (size_t)bm * K_DIM;
    const char* gB = Bt + (size_t)bn * K_DIM;
    // staging: thread t covers row (t&255), k-chunks (t>>8) and (t>>8)+2
    const int voff = (t & 255) * K_DIM + ((t >> 8) << 4);

    // fragment read offsets within a 16K buffer ([kc 0..3][row 0..255][16B])
    const int aoff = lg2 * 4096 + ((wm * 128 + ln31) << 4);
    const int boff = lg2 * 4096 + ((wn * 64 + ln31) << 4);

#define STAGE_A(abi, kt)                                                      \
    do {                                                                      \
        GLOAD_LDS16(gA + (size_t)(kt) * 64 + voff,                            \
                    lds + (abi) * 16384 + t * 16);                            \
        GLOAD_LDS16(gA + (size_t)(kt) * 64 + voff + 32,                       \
                    lds + (abi) * 16384 + 8192 + t * 16);                     \
    } while (0)

#define STAGE_B(bbi, kt)                                                      \
    do {                                                                      \
        GLOAD_LDS16(gB + (size_t)(kt) * 64 + voff,                            \
                    lds + 32768 + (bbi) * 16384 + t * 16);                    \
        GLOAD_LDS16(gB + (size_t)(kt) * 64 + voff + 32,                       \
                    lds + 32768 + (bbi) * 16384 + 8192 + t * 16);             \
    } while (0)

#define LD(p) (*reinterpret_cast<const i32x4*>(p))

#define READ_A(par, ks, mfp)                                                  \
    do {                                                                      \
        afr[par][0] = LD(ab + (ks) * 8192 + ((mfp) * 2) * 512 + aoff);        \
        afr[par][1] = LD(ab + (ks) * 8192 + ((mfp) * 2 + 1) * 512 + aoff);    \
    } while (0)

#define READ_BAHEAD(BNXT, bnbi)                                               \
    do {                                                                      \
        const char* bn_ = lds + 32768 + (bnbi) * 16384;                       \
        _Pragma("unroll")                                                     \
        for (int ks = 0; ks < 2; ++ks)                                        \
            _Pragma("unroll")                                                 \
            for (int nf = 0; nf < 2; ++nf)                                    \
                BNXT[ks * 2 + nf] = LD(bn_ + ks * 8192 + nf * 512 + boff);    \
    } while (0)

#define MFMA4(par, ks, mfp, BCUR)                                             \
    do {                                                                      \
        __builtin_amdgcn_s_setprio(1);                                        \
        _Pragma("unroll")                                                     \
        for (int m2 = 0; m2 < 2; ++m2)                                        \
            _Pragma("unroll")                                                 \
            for (int nf = 0; nf < 2; ++nf)                                    \
                acc[(mfp) * 2 + m2][nf] =                                     \
                    __builtin_amdgcn_mfma_i32_32x32x32_i8(                    \
                        afr[par][m2], BCUR[(ks) * 2 + nf],                    \
                        acc[(mfp) * 2 + m2][nf], 0, 0, 0);                    \
        __builtin_amdgcn_s_setprio(0);                                        \
    } while (0)

// AB: A buf (0/1); SBB: B stage buf; BNB: B-ahead src buf;
// BCUR/BNXT: current/next B-frag register arrays; STA/STB/RDB: flags;
// VM: end vmcnt imm (2 or 0); tt: runtime K-tile index.
#define TILE(AB, SBB, BNB, BCUR, BNXT, STA, STB, RDB, VM, tt)                 \
    do {                                                                      \
        const char* ab = lds + (AB) * 16384;                                  \
        READ_A(0, 0, 0);                                                      \
        /* p0 */ READ_A(1, 0, 1);                                             \
        if (STA) STAGE_A((AB) ^ 1, (tt) + 1);                                 \
        if (STB) STAGE_B(SBB, (tt) + 3);                                      \
        WAIT_LGKM(2); MFMA4(0, 0, 0, BCUR);                                   \
        /* p1 */ READ_A(0, 1, 0); WAIT_LGKM(2); MFMA4(1, 0, 1, BCUR);         \
        /* p2 */ READ_A(1, 1, 1); WAIT_LGKM(2); MFMA4(0, 1, 0, BCUR);         \
        /* p3 */ if (RDB) { READ_BAHEAD(BNXT, BNB); WAIT_LGKM(4); }           \
                 else     { WAIT_LGKM(0); }                                   \
        MFMA4(1, 1, 1, BCUR);                                                 \
        asm volatile("s_waitcnt vmcnt(" #VM ")" ::: "memory");                \
        BARRIER();                                                            \
    } while (0)

    i32x16 acc[4][2];
#pragma unroll
    for (int m = 0; m < 4; ++m)
#pragma unroll
        for (int n = 0; n < 2; ++n)
#pragma unroll
            for (int q = 0; q < 16; ++q)
                acc[m][n][q] = 0;

    i32x4 afr[2][2];
    i32x4 bfrA[4], bfrB[4];

    // prologue: A(0)->a0, B(0),B(1),B(2) -> b0,b1,b2; force all but B(2);
    // publish; pre-read B(0) frags into bfrA (tile 0's current).
    STAGE_A(0, 0); STAGE_B(0, 0); STAGE_B(1, 1); STAGE_B(2, 2);
    asm volatile("s_waitcnt vmcnt(2)" ::: "memory");
    BARRIER();
    READ_BAHEAD(bfrA, 0);

    // tiles 0..59 in 15 groups of 4 (A parity 2 x B parity 4), all full
    for (int kt = 0; kt < NT - 4; kt += 4) {
        TILE(0, 3, 1, bfrA, bfrB, 1, 1, 1, 2, kt);       // t%4==0: b0, stage b3
        TILE(1, 0, 2, bfrB, bfrA, 1, 1, 1, 2, kt + 1);   // b1, stage b0
        TILE(0, 1, 3, bfrA, bfrB, 1, 1, 1, 2, kt + 2);   // b2, stage b1
        TILE(1, 2, 0, bfrB, bfrA, 1, 1, 1, 2, kt + 3);   // b3, stage b2
    }
    // tail tiles 60..63
    TILE(0, 3, 1, bfrA, bfrB, 1, 1, 1, 2, NT - 4);   // 60: stage A61,B63; ahead B61
    TILE(1, 0, 2, bfrB, bfrA, 1, 0, 1, 0, NT - 3);   // 61: stage A62; ahead B62
    TILE(0, 1, 3, bfrA, bfrB, 1, 0, 1, 0, NT - 2);   // 62: stage A63; ahead B63
    TILE(1, 2, 0, bfrB, bfrA, 0, 0, 0, 0, NT - 1);   // 63: compute only

    // ---- epilogue: 32x32 C/D layout: col=lane&31,
    //      row = (reg&3) + 8*(reg>>2) + 4*(lane>>5) ----
    const float scale = beta_p[0] * gamma_p[0] * (1.0f / QBf);
    const int orow0 = bm + wm * 128 + lg2 * 4;
    const int ocol0 = bn + wn * 64 + ln31;
#pragma unroll
    for (int mf = 0; mf < 4; ++mf) {
#pragma unroll
        for (int nf = 0; nf < 2; ++nf) {
#pragma unroll
            for (int reg = 0; reg < 16; ++reg) {
                const int row = orow0 + mf * 32 + (reg & 3) + 8 * (reg >> 2);
                C[(size_t)row * N_DIM + ocol0 + nf * 32] =
                    (float)acc[mf][nf][reg] * scale;
            }
        }
    }
#undef STAGE_A
#undef STAGE_B
#undef LD
#undef READ_A
#undef READ_BAHEAD
#undef MFMA4
#undef TILE
}

// ---------------------------------------------------------------------------
extern "C" void kernel_launch(void* const* d_in, const int* in_sizes, int n_in,
                              void* d_out, int out_size, void* d_ws, size_t ws_size,
                              hipStream_t stream)
{
    const float* x       = (const float*)d_in[0];
    const float* w       = (const float*)d_in[1];
    const float* ln_g    = (const float*)d_in[2];
    const float* ln_b    = (const float*)d_in[3];
    const float* beta_p  = (const float*)d_in[4];
    const float* gamma_p = (const float*)d_in[5];
    float* out = (float*)d_out;

    const int M = in_sizes[0] / K_DIM;   // 8192

    char* xq = (char*)d_ws;
    char* wq = (char*)d_ws + (size_t)M * K_DIM;

    ln_quant_kernel<<<M, 256, 0, stream>>>(x, ln_g, ln_b, gamma_p, xq);
    wtrans_kernel<<<dim3(N_DIM / 64, K_DIM / 64), 256, 0, stream>>>(w, wq);
    gemm_kernel<<<dim3(N_DIM / 256, M / 256), 512, 0, stream>>>(xq, wq, out, beta_p, gamma_p);
}

// Round 15
// 249.358 us; speedup vs baseline: 1.0513x; 1.0240x over previous
//
#include <hip/hip_runtime.h>

using i32x4  = __attribute__((ext_vector_type(4))) int;
using i32x16 = __attribute__((ext_vector_type(16))) int;

constexpr int K_DIM = 4096;   // N_IN
constexpr int N_DIM = 4096;   // N_OUT
constexpr float QBf = 128.0f;
constexpr float EPf = 0.01f;
constexpr float LN_EPSf = 1e-5f;

#define GLOAD_LDS16(gp, lp)                                                  \
    __builtin_amdgcn_global_load_lds(                                        \
        (const __attribute__((address_space(1))) void*)(gp),                 \
        (__attribute__((address_space(3))) void*)(lp), 16, 0, 0)

#define BARRIER()                                                            \
    do { asm volatile("" ::: "memory");                                      \
         __builtin_amdgcn_s_barrier();                                       \
         asm volatile("" ::: "memory"); } while (0)

#define WAIT_LGKM0()                                                         \
    do { asm volatile("s_waitcnt lgkmcnt(0)" ::: "memory");                  \
         __builtin_amdgcn_sched_barrier(0); } while (0)

// ---------------------------------------------------------------------------
// Kernel 1: fused LayerNorm + ABSMax-quant + round-to-int8.  One block/row.
// ---------------------------------------------------------------------------
__global__ __launch_bounds__(256) void ln_quant_kernel(
    const float* __restrict__ x,
    const float* __restrict__ ln_g,
    const float* __restrict__ ln_b,
    const float* __restrict__ gamma_p,
    char* __restrict__ xq)
{
    const int row = blockIdx.x;
    const int t = threadIdx.x;
    const float4* xr4 = reinterpret_cast<const float4*>(x + (size_t)row * K_DIM);

    float4 v[4];
    float sum = 0.f, sumsq = 0.f;
#pragma unroll
    for (int i = 0; i < 4; ++i) {
        v[i] = xr4[t * 4 + i];
        sum += v[i].x + v[i].y + v[i].z + v[i].w;
        sumsq += v[i].x * v[i].x + v[i].y * v[i].y + v[i].z * v[i].z + v[i].w * v[i].w;
    }
#pragma unroll
    for (int off = 32; off > 0; off >>= 1) {
        sum += __shfl_down(sum, off);
        sumsq += __shfl_down(sumsq, off);
    }
    __shared__ float s_sum[4], s_sq[4];
    const int lane = t & 63, w = t >> 6;
    if (lane == 0) { s_sum[w] = sum; s_sq[w] = sumsq; }
    __syncthreads();
    sum = s_sum[0] + s_sum[1] + s_sum[2] + s_sum[3];
    sumsq = s_sq[0] + s_sq[1] + s_sq[2] + s_sq[3];

    const float mu = sum * (1.0f / K_DIM);
    const float var = sumsq * (1.0f / K_DIM) - mu * mu;
    const float rstd = rsqrtf(var + LN_EPSf);
    const float qs = QBf / gamma_p[0];
    const float lo = -QBf + EPf, hi = QBf - EPf;

    alignas(16) char ob[16];
#pragma unroll
    for (int i = 0; i < 4; ++i) {
        const float4 g = reinterpret_cast<const float4*>(ln_g)[t * 4 + i];
        const float4 b = reinterpret_cast<const float4*>(ln_b)[t * 4 + i];
        const float f0 = fminf(fmaxf(((v[i].x - mu) * rstd * g.x + b.x) * qs, lo), hi);
        const float f1 = fminf(fmaxf(((v[i].y - mu) * rstd * g.y + b.y) * qs, lo), hi);
        const float f2 = fminf(fmaxf(((v[i].z - mu) * rstd * g.z + b.z) * qs, lo), hi);
        const float f3 = fminf(fmaxf(((v[i].w - mu) * rstd * g.w + b.w) * qs, lo), hi);
        int x0 = (int)rintf(f0), x1 = (int)rintf(f1);
        int x2 = (int)rintf(f2), x3 = (int)rintf(f3);
        ob[i * 4 + 0] = (char)(x0 > 127 ? 127 : x0);
        ob[i * 4 + 1] = (char)(x1 > 127 ? 127 : x1);
        ob[i * 4 + 2] = (char)(x2 > 127 ? 127 : x2);
        ob[i * 4 + 3] = (char)(x3 > 127 ? 127 : x3);
    }
    *reinterpret_cast<uint4*>(xq + (size_t)row * K_DIM + t * 16) =
        *reinterpret_cast<const uint4*>(ob);
}

// ---------------------------------------------------------------------------
// Kernel 2: w (fp32, K x N, values ±1) -> wq (int8, N x K).  64x64 tiles.
// ---------------------------------------------------------------------------
__global__ __launch_bounds__(256) void wtrans_kernel(
    const float* __restrict__ w, char* __restrict__ wq)
{
    __shared__ char tile[64][68];
    const int t = threadIdx.x;
    const int bk = blockIdx.y * 64;
    const int bn = blockIdx.x * 64;
#pragma unroll
    for (int i = 0; i < 4; ++i) {
        const int li = i * 1024 + t * 4;
        const int r = li >> 6, c = li & 63;    // r = k-in-tile, c = n-in-tile
        const float4 vv = *reinterpret_cast<const float4*>(
            w + (size_t)(bk + r) * N_DIM + bn + c);
        tile[r][c]     = (char)vv.x;
        tile[r][c + 1] = (char)vv.y;
        tile[r][c + 2] = (char)vv.z;
        tile[r][c + 3] = (char)vv.w;
    }
    __syncthreads();
    const int n = t >> 2, kc = t & 3;
    alignas(16) char h16[16];
#pragma unroll
    for (int j = 0; j < 16; ++j) h16[j] = tile[kc * 16 + j][n];
    *reinterpret_cast<uint4*>(wq + (size_t)(bn + n) * K_DIM + bk + kc * 16) =
        *reinterpret_cast<const uint4*>(h16);
}

// ---------------------------------------------------------------------------
// Kernel 3: GEMM  C[M,N] = A[M,K] * Bt[N,K]^T * scale  (i8 MFMA, i32 acc)
// 256x256 tile, BK=128 bytes (32 K-tiles), 512 threads = 8 waves (2M x 4N),
// wave tile 128x64 (4 mf x 2 nf x 4 ks = 32 mfma_i32_32x32x32_i8 / K-tile).
// m201-faithful FAT-PHASE schedule: 2 phases per K-tile, each phase =
//   { 12 ds_read_b128 (A 8 + B 4, THIS phase's ks-pair)
//   | 4 global_load_lds (stage half of tile t+1: A at ph0, B at ph1)
//   | BARRIER | lgkmcnt(0)+sched_barrier | setprio(1) | 16 MFMA | setprio(0) }
// and the tile ends with vmcnt(0) | BARRIER.
// Why fat phases: one 16-MFMA burst = ~1170 cy of SIMD pipe time (i8 32x32x32
// = ~37 cy/instr) vs ONE ~150 cy read-latency+barrier toll -> predicted
// ~75% util ceiling, vs 8 thin sub-phases paying the toll 8x (R11's 36%).
// vmcnt(0) safety: STAGE_A issued at ph0 has ~2400 cy of MFMA cover, STAGE_B
// ~1300 cy -- both exceed HBM-miss latency, so the drain finds loads landed.
// WAR: buf^1's readers (tile t-1) all complete before t-1's final BARRIER.
// RAW: t+1 reads buf^1 only after t's vmcnt(0)+BARRIER.
// LDS 2 bufs x (A 32K | B 32K) = 128 KiB.  Region layout [kc 0..7][row][16B]
// (kc-plane 4KB): staging dest = r*8192 + t*16 (linear); every 32-lane frag
// read is 512 contiguous bytes -> zero bank conflicts by construction.
// ---------------------------------------------------------------------------
__global__ __launch_bounds__(512, 2) void gemm_kernel(
    const char* __restrict__ A,
    const char* __restrict__ Bt,
    float* __restrict__ C,
    const float* __restrict__ beta_p,
    const float* __restrict__ gamma_p)
{
    constexpr int NT = K_DIM / 128;                // 32 K-tiles
    __shared__ __align__(16) char lds[131072];     // 2 bufs x (A 32K | B 32K)

    const int t = threadIdx.x;
    // ---- XCD swizzle: flat id -> 8x8 square per XCD (512 blocks, 16x32 grid)
    const int flat = blockIdx.y * gridDim.x + blockIdx.x;
    const int xcd = flat & 7;
    const int r8 = flat >> 3;                       // 0..63
    const int by = ((xcd >> 1) << 3) + (r8 >> 3);   // 0..31  (M index)
    const int bx = ((xcd & 1) << 3) + (r8 & 7);     // 0..15  (N index)
    const int bm = by * 256;
    const int bn = bx * 256;

    const int lane = t & 63;
    const int w = t >> 6;
    const int wm = w >> 2;            // 0..1
    const int wn = w & 3;             // 0..3
    const int ln31 = lane & 31;
    const int lg2 = lane >> 5;        // 0..1

    const char* gA = A + (size_t)bm * K_DIM;
    const char* gB = Bt + (size_t)bn * K_DIM;
    // staging: thread t covers row (t&255), k-chunk (t>>8)+2r; dest r*8192+t*16
    const int voff = (t & 255) * K_DIM + ((t >> 8) << 4);

    // fragment read offsets ([kc][row][16B], kc = ks*2 + lg2, plane 4KB)
    const int aoff = lg2 * 4096 + ((wm * 128 + ln31) << 4);
    const int boff = lg2 * 4096 + ((wn * 64 + ln31) << 4);

#define STAGE_A(b, kt)                                                        \
    do {                                                                      \
        _Pragma("unroll")                                                     \
        for (int r = 0; r < 4; ++r)                                           \
            GLOAD_LDS16(gA + (size_t)(kt) * 128 + voff + r * 32,              \
                        lds + (b) * 65536 + r * 8192 + t * 16);               \
    } while (0)

#define STAGE_B(b, kt)                                                        \
    do {                                                                      \
        _Pragma("unroll")                                                     \
        for (int r = 0; r < 4; ++r)                                           \
            GLOAD_LDS16(gB + (size_t)(kt) * 128 + voff + r * 32,              \
                        lds + (b) * 65536 + 32768 + r * 8192 + t * 16);       \
    } while (0)

#define LD(p) (*reinterpret_cast<const i32x4*>(p))

// read all 12 frags for ks-pair `ph` (ks = 2*ph, 2*ph+1)
#define READ_PH(ph)                                                           \
    do {                                                                      \
        _Pragma("unroll")                                                     \
        for (int k2 = 0; k2 < 2; ++k2) {                                      \
            _Pragma("unroll")                                                 \
            for (int mf = 0; mf < 4; ++mf)                                    \
                afr[k2][mf] = LD(ab + ((ph) * 2 + k2) * 8192 + mf * 512 + aoff); \
            _Pragma("unroll")                                                 \
            for (int nf = 0; nf < 2; ++nf)                                    \
                bfr[k2][nf] = LD(bb + ((ph) * 2 + k2) * 8192 + nf * 512 + boff); \
        }                                                                     \
    } while (0)

#define MFMA_PH()                                                             \
    do {                                                                      \
        __builtin_amdgcn_s_setprio(1);                                        \
        _Pragma("unroll")                                                     \
        for (int k2 = 0; k2 < 2; ++k2)                                        \
            _Pragma("unroll")                                                 \
            for (int mf = 0; mf < 4; ++mf)                                    \
                _Pragma("unroll")                                             \
                for (int nf = 0; nf < 2; ++nf)                                \
                    acc[mf][nf] = __builtin_amdgcn_mfma_i32_32x32x32_i8(      \
                        afr[k2][mf], bfr[k2][nf], acc[mf][nf], 0, 0, 0);      \
        __builtin_amdgcn_s_setprio(0);                                        \
    } while (0)

#define TILE(b, tt)                                                           \
    do {                                                                      \
        const char* ab = lds + (b) * 65536;                                   \
        const char* bb = ab + 32768;                                          \
        i32x4 afr[2][4], bfr[2][2];                                           \
        /* phase 0: ks 0,1 */                                                 \
        READ_PH(0);                                                           \
        if ((tt) + 1 < NT) STAGE_A((b) ^ 1, (tt) + 1);                        \
        BARRIER();                                                            \
        WAIT_LGKM0();                                                         \
        MFMA_PH();                                                            \
        /* phase 1: ks 2,3 */                                                 \
        READ_PH(1);                                                           \
        if ((tt) + 1 < NT) STAGE_B((b) ^ 1, (tt) + 1);                        \
        BARRIER();                                                            \
        WAIT_LGKM0();                                                         \
        MFMA_PH();                                                            \
        if ((tt) + 1 < NT) asm volatile("s_waitcnt vmcnt(0)" ::: "memory");   \
        BARRIER();                                                            \
    } while (0)

    i32x16 acc[4][2];
#pragma unroll
    for (int m = 0; m < 4; ++m)
#pragma unroll
        for (int n = 0; n < 2; ++n)
#pragma unroll
            for (int q = 0; q < 16; ++q)
                acc[m][n][q] = 0;

    // prologue: stage tile 0 into buf0; drain; sync
    STAGE_A(0, 0); STAGE_B(0, 0);
    asm volatile("s_waitcnt vmcnt(0)" ::: "memory");
    BARRIER();

    for (int kt = 0; kt < NT; kt += 2) {
        TILE(0, kt);
        TILE(1, kt + 1);
    }

    // ---- epilogue: 32x32 C/D layout: col=lane&31,
    //      row = (reg&3) + 8*(reg>>2) + 4*(lane>>5) ----
    const float scale = beta_p[0] * gamma_p[0] * (1.0f / QBf);
    const int orow0 = bm + wm * 128 + lg2 * 4;
    const int ocol0 = bn + wn * 64 + ln31;
#pragma unroll
    for (int mf = 0; mf < 4; ++mf) {
#pragma unroll
        for (int nf = 0; nf < 2; ++nf) {
#pragma unroll
            for (int reg = 0; reg < 16; ++reg) {
                const int row = orow0 + mf * 32 + (reg & 3) + 8 * (reg >> 2);
                C[(size_t)row * N_DIM + ocol0 + nf * 32] =
                    (float)acc[mf][nf][reg] * scale;
            }
        }
    }
#undef STAGE_A
#undef STAGE_B
#undef LD
#undef READ_PH
#undef MFMA_PH
#undef TILE
}

// ---------------------------------------------------------------------------
extern "C" void kernel_launch(void* const* d_in, const int* in_sizes, int n_in,
                              void* d_out, int out_size, void* d_ws, size_t ws_size,
                              hipStream_t stream)
{
    const float* x       = (const float*)d_in[0];
    const float* w       = (const float*)d_in[1];
    const float* ln_g    = (const float*)d_in[2];
    const float* ln_b    = (const float*)d_in[3];
    const float* beta_p  = (const float*)d_in[4];
    const float* gamma_p = (const float*)d_in[5];
    float* out = (float*)d_out;

    const int M = in_sizes[0] / K_DIM;   // 8192

    char* xq = (char*)d_ws;
    char* wq = (char*)d_ws + (size_t)M * K_DIM;

    ln_quant_kernel<<<M, 256, 0, stream>>>(x, ln_g, ln_b, gamma_p, xq);
    wtrans_kernel<<<dim3(N_DIM / 64, K_DIM / 64), 256, 0, stream>>>(w, wq);
    gemm_kernel<<<dim3(N_DIM / 256, M / 256), 512, 0, stream>>>(xq, wq, out, beta_p, gamma_p);
}